// Round 1
// baseline (609.297 us; speedup 1.0000x reference)
//
#include <hip/hip_runtime.h>
#include <cstdint>
#include <cstddef>

// Problem constants
#define TT   2048
#define BB   64
#define KK   512
#define OO   512
#define OT   64      // o-range per block
#define NCH  128     // time chunks
#define TC   16      // t-steps per chunk
#define LJ   8       // pair-iterations per chunk (2 t-steps each)

typedef __attribute__((ext_vector_type(8))) short short8;
typedef __attribute__((ext_vector_type(4))) float f32x4;

__device__ __forceinline__ unsigned short f2bf(float f) {
  unsigned int u = __float_as_uint(f);
  unsigned int rounding = 0x7FFFu + ((u >> 16) & 1u);
  return (unsigned short)((u + rounding) >> 16);
}

__device__ __forceinline__ float sigmoid_f(float z) {
  return 1.0f / (1.0f + __expf(-z));
}

__device__ __forceinline__ float tanh_f(float z) {
  z = fminf(15.0f, fmaxf(-15.0f, z));
  float e = __expf(-2.0f * z);
  return (1.0f - e) / (1.0f + e);
}

__device__ __forceinline__ void async_ld16(const void* g, void* l) {
  __builtin_amdgcn_global_load_lds(
      (const __attribute__((address_space(1))) void*)g,
      (__attribute__((address_space(3))) void*)l, 16, 0, 0);
}

// ---------------- kernel 1: x fp32 -> bf16 ----------------
__global__ void convert_x_k(const float4* __restrict__ x4,
                            ushort4* __restrict__ xb4, int n4) {
  int i = blockIdx.x * blockDim.x + threadIdx.x;
  int stride = gridDim.x * blockDim.x;
  for (; i < n4; i += stride) {
    float4 v = x4[i];
    ushort4 o;
    o.x = f2bf(v.x); o.y = f2bf(v.y); o.z = f2bf(v.z); o.w = f2bf(v.w);
    xb4[i] = o;
  }
}

// ---------------- kernel 2: transpose+convert weights ----------------
// Gt[o][k] = bf16(g[k][o]); Ht likewise. grid (16,16,2), block (32,8)
__global__ void prep_weights_k(const float* __restrict__ g,
                               const float* __restrict__ h,
                               unsigned short* __restrict__ Gt,
                               unsigned short* __restrict__ Ht) {
  __shared__ float tile[32][33];
  const float* src = (blockIdx.z == 0) ? g : h;
  unsigned short* dst = (blockIdx.z == 0) ? Gt : Ht;
  int ox = blockIdx.x * 32;   // o base
  int ky = blockIdx.y * 32;   // k base
  int tx = threadIdx.x, ty = threadIdx.y;
  #pragma unroll
  for (int r = ty; r < 32; r += 8)
    tile[r][tx] = src[(ky + r) * OO + ox + tx];
  __syncthreads();
  #pragma unroll
  for (int r = ty; r < 32; r += 8)
    dst[(size_t)(ox + r) * KK + ky + tx] = f2bf(tile[tx][r]);
}

// ---------------- kernel 3: fused GEMM + gates + chunk scan ----------------
__global__ __launch_bounds__(256, 2) void rnn_fused_k(
    const unsigned short* __restrict__ xb,   // [T*B][K] bf16
    const unsigned short* __restrict__ Gt,   // [OO][KK] bf16
    const unsigned short* __restrict__ Ht,   // [OO][KK] bf16
    const float* __restrict__ gb, const float* __restrict__ hb,
    const float* __restrict__ r,  const float* __restrict__ rb,
    float* __restrict__ chunkA, float* __restrict__ chunkB) {
  __shared__ __align__(16) unsigned short Atile[128 * 64];  // 16 KB
  __shared__ __align__(16) unsigned short Btile[128 * 64];  // 16 KB

  const int tid  = threadIdx.x;
  const int wave = tid >> 6;
  const int lane = tid & 63;
  const int quad = lane >> 4;
  const int lcol = lane & 15;
  const int ot = blockIdx.x & 7;
  const int c  = blockIdx.x >> 3;
  const int o0 = ot * OT;
  const int o  = o0 + wave * 16 + lcol;   // this thread's output column

  const float gbv = gb[o], hbv = hb[o];
  const float rv  = r[o],  rbv = rb[o];

  // chunk-scan state per (b,o) slot: y_out = SB + SA*y_in
  float SA[16], SB[16];
  #pragma unroll
  for (int s = 0; s < 16; s++) { SA[s] = 1.0f; SB[s] = 0.0f; }

  const int srow = lane >> 3;   // 0..7 within 8-row staging group
  const int schunk = lane & 7;  // 16B chunk slot in LDS row

  for (int j = 0; j < LJ; j++) {
    const int t0 = c * TC + j * 2;
    const long R0 = (long)t0 * BB;   // x row base (= t0*64)

    f32x4 acc[8][2];
    #pragma unroll
    for (int m = 0; m < 8; m++) {
      f32x4 z = {0.0f, 0.0f, 0.0f, 0.0f};
      acc[m][0] = z; acc[m][1] = z;
    }

    for (int kc = 0; kc < 8; kc++) {
      __syncthreads();   // protect LDS from previous iteration's readers
      // stage A: 128 rows x 64 k (bf16), XOR-swizzled 16B chunks
      #pragma unroll
      for (int i = 0; i < 4; i++) {
        int row = wave * 32 + i * 8 + srow;            // 0..127
        int gchunk = schunk ^ (row & 7);
        const unsigned short* gp =
            xb + (R0 + row) * (long)KK + kc * 64 + gchunk * 8;
        async_ld16(gp, &Atile[(wave * 32 + i * 8) * 64]);
      }
      // stage B: rows 0..63 = Gt[o0..o0+63], rows 64..127 = Ht[o0..o0+63]
      #pragma unroll
      for (int i = 0; i < 4; i++) {
        int row = wave * 32 + i * 8 + srow;
        int gchunk = schunk ^ (row & 7);
        const unsigned short* Wb = (wave < 2) ? Gt : Ht;  // wave-uniform
        int wrow = o0 + (row & 63);
        const unsigned short* gp =
            Wb + (size_t)wrow * KK + kc * 64 + gchunk * 8;
        async_ld16(gp, &Btile[(wave * 32 + i * 8) * 64]);
      }
      __syncthreads();   // includes vmcnt(0) drain of global_load_lds

      #pragma unroll
      for (int ks = 0; ks < 2; ks++) {
        int lchunk = ks * 4 + quad;  // logical 16B chunk (k = ks*32+quad*8)
        int bgrow = wave * 16 + lcol;
        short8 bg = *(const short8*)&Btile[bgrow * 64 + ((lchunk ^ (bgrow & 7)) * 8)];
        int bhrow = 64 + wave * 16 + lcol;
        short8 bh = *(const short8*)&Btile[bhrow * 64 + ((lchunk ^ (bhrow & 7)) * 8)];
        #pragma unroll
        for (int m = 0; m < 8; m++) {
          int arow = m * 16 + lcol;
          short8 a = *(const short8*)&Atile[arow * 64 + ((lchunk ^ (arow & 7)) * 8)];
          acc[m][0] = __builtin_amdgcn_mfma_f32_16x16x32_bf16(a, bg, acc[m][0], 0, 0, 0);
          acc[m][1] = __builtin_amdgcn_mfma_f32_16x16x32_bf16(a, bh, acc[m][1], 0, 0, 0);
        }
      }
    }

    // epilogue: activations + time gate + compose the 2 steps into state
    const float rt0 = 2.0f * sigmoid_f(((float)t0       * (1.0f / TT)) * rv + rbv);
    const float rt1 = 2.0f * sigmoid_f(((float)(t0 + 1) * (1.0f / TT)) * rv + rbv);
    #pragma unroll
    for (int mq = 0; mq < 4; mq++) {
      #pragma unroll
      for (int reg = 0; reg < 4; reg++) {
        float G0 = sigmoid_f(acc[mq][0][reg] + gbv) * rt0;
        float H0 = tanh_f  (acc[mq][1][reg] + hbv) * rt0;
        float G1 = sigmoid_f(acc[mq + 4][0][reg] + gbv) * rt1;
        float H1 = tanh_f  (acc[mq + 4][1][reg] + hbv) * rt1;
        float pA = G1 * G0;
        float pB = fmaf(G1, H0, H1);
        int s = mq * 4 + reg;
        SB[s] = fmaf(pA, SB[s], pB);
        SA[s] *= pA;
      }
    }
  }

  // write chunk composition: layout [c][b][o]
  #pragma unroll
  for (int s = 0; s < 16; s++) {
    int b = (s >> 2) * 16 + quad * 4 + (s & 3);
    size_t idx = ((size_t)c * BB + b) * OO + o;
    chunkA[idx] = SA[s];
    chunkB[idx] = SB[s];
  }
}

// ---------------- kernel 4: fold chunks ----------------
__global__ void combine_k(const float* __restrict__ cA,
                          const float* __restrict__ cB,
                          float* __restrict__ out) {
  int i = blockIdx.x * blockDim.x + threadIdx.x;  // b*OO + o
  float y = 0.0f;
  for (int c = 0; c < NCH; c++) {
    float A  = cA[(size_t)c * (BB * OO) + i];
    float Bv = cB[(size_t)c * (BB * OO) + i];
    y = fmaf(A, y, Bv);
  }
  out[i] = y;
}

extern "C" void kernel_launch(void* const* d_in, const int* in_sizes, int n_in,
                              void* d_out, int out_size, void* d_ws, size_t ws_size,
                              hipStream_t stream) {
  (void)in_sizes; (void)n_in; (void)out_size; (void)ws_size;
  const float* x  = (const float*)d_in[0];
  const float* g  = (const float*)d_in[1];
  const float* gb = (const float*)d_in[2];
  const float* h  = (const float*)d_in[3];
  const float* hb = (const float*)d_in[4];
  const float* r  = (const float*)d_in[5];
  const float* rb = (const float*)d_in[6];
  float* out = (float*)d_out;

  char* w = (char*)d_ws;
  unsigned short* xb = (unsigned short*)w;                       // 134217728 B
  unsigned short* Gt = (unsigned short*)(w + 134217728);         // 524288 B
  unsigned short* Ht = (unsigned short*)(w + 134742016);         // 524288 B
  float* chunkA = (float*)(w + 135266304);                       // 16777216 B
  float* chunkB = (float*)(w + 152043520);                       // 16777216 B
  // total: 168820736 B

  const int n4 = (TT * BB * KK) / 4;  // 16777216 float4s
  convert_x_k<<<8192, 256, 0, stream>>>((const float4*)x, (ushort4*)xb, n4);
  prep_weights_k<<<dim3(16, 16, 2), dim3(32, 8), 0, stream>>>(g, h, Gt, Ht);
  rnn_fused_k<<<NCH * (OO / OT), 256, 0, stream>>>(xb, Gt, Ht, gb, hb, r, rb,
                                                   chunkA, chunkB);
  combine_k<<<(BB * OO) / 256, 256, 0, stream>>>(chunkA, chunkB, out);
}